// Round 9
// baseline (6953.182 us; speedup 1.0000x reference)
//
#include <hip/hip_runtime.h>
#include <hip/hip_bf16.h>
#include <hip/hip_cooperative_groups.h>

namespace cg = cooperative_groups;

// ---------------------------------------------------------------------------
// VisionMamba, round 8: cooperative mega-kernel.
// B=8, L=196, D_MODEL=192, D_INNER=384, D_STATE=16, DT_RANK=12, DEPTH=24.
//
// R8 change: the 96 per-layer dispatches (4/layer x 24) were costing ~6us
// each in launch/ramp/drain overhead (~600us of 1465). All 24 layers now run
// in ONE hipLaunchCooperativeKernel (grid 256x256), with cg::grid().sync()
// between stages. Stage bodies are verbatim R7 kernels looped over virtual
// block indices; 69KB LDS union (scan is the max); 2 blocks/CU co-resident.
// Pre-stage (cvt_weights, im2col, patch-embed gemm_ln<768>) stays separate.
// ---------------------------------------------------------------------------

#define NTOK   1568   // B * L
#define DMODEL 192
#define DINNER 384
#define DSTATE 16
#define DTRANK 12
#define DEPTH  24
#define LSEQ   196
#define TCH    49     // scan time-chunk (196 = 4*49)
#define LDA    40     // LDS row stride in bf16 elements (80B)

typedef __attribute__((ext_vector_type(8))) short short8;
typedef __attribute__((ext_vector_type(4))) short short4v;
typedef __attribute__((ext_vector_type(4))) float floatx4;

__device__ inline short f2bf(float f) {
    __hip_bfloat16 h = __float2bfloat16(f);
    return *reinterpret_cast<short*>(&h);
}

// ---------------- weight fp32 -> bf16 conversion (in/out/pe) ----------------
#define CVT_N1 884736   // in_proj  24*768*192 /4
#define CVT_N2 442368   // out_proj 24*192*384 /4
#define CVT_N3 36864    // pe       192*768    /4
__global__ __launch_bounds__(256) void cvt_weights(
    const float* __restrict__ inw, const float* __restrict__ outw,
    const float* __restrict__ pew,
    short* __restrict__ w_in, short* __restrict__ w_out,
    short* __restrict__ w_pe)
{
    int idx = blockIdx.x * 256 + threadIdx.x;
    float4 v;
    short* dst;
    if (idx < CVT_N1) {
        v = ((const float4*)inw)[idx]; dst = w_in + (size_t)idx * 4;
    } else if (idx < CVT_N1 + CVT_N2) {
        int i = idx - CVT_N1;
        v = ((const float4*)outw)[i]; dst = w_out + (size_t)i * 4;
    } else if (idx < CVT_N1 + CVT_N2 + CVT_N3) {
        int i = idx - CVT_N1 - CVT_N2;
        v = ((const float4*)pew)[i]; dst = w_pe + (size_t)i * 4;
    } else {
        return;
    }
    short4v o;
    o[0] = f2bf(v.x); o[1] = f2bf(v.y); o[2] = f2bf(v.z); o[3] = f2bf(v.w);
    *(short4v*)dst = o;
}

// ---------------- im2col for patch embed (bf16 out) ----------------
__global__ __launch_bounds__(256) void im2col(
    const float* __restrict__ x, __hip_bfloat16* __restrict__ patches)
{
    int idx = blockIdx.x * 256 + threadIdx.x;
    if (idx >= NTOK * 768) return;
    int tok = idx / 768, e = idx % 768;
    int b = tok / LSEQ, l = tok % LSEQ;
    int py = l / 14, px = l % 14;
    int ic = e >> 8, rem = e & 255, ky = rem >> 4, kx = rem & 15;
    patches[idx] = __float2bfloat16(x[((b * 3 + ic) * 224 + py * 16 + ky) * 224 + px * 16 + kx]);
}

// ---------------- standalone gemm_ln (patch embed only, K=768) ----------------
template<int K>
__global__ __launch_bounds__(256) void gemm_ln_pe(
    const __hip_bfloat16* __restrict__ A, const short* __restrict__ Wb,
    const float* __restrict__ bias, float* __restrict__ residual,
    __hip_bfloat16* __restrict__ hn,
    const float* __restrict__ lnw, const float* __restrict__ lnb)
{
    __shared__ short As[16 * LDA];
    __shared__ short Ws[192 * LDA];
    __shared__ float slw[192], slb[192], sbias[192];
    __shared__ float sS1[4][16], sS2[4][16];
    int tid = threadIdx.x;
    int m0 = blockIdx.x * 16;
    int wv = tid >> 6, lane = tid & 63;
    int fm = lane & 15, q = lane >> 4;
    int wrow = tid >> 2, kc = (tid & 3) * 8;
    if (tid < 192) {
        slw[tid] = lnw[tid];
        slb[tid] = lnb[tid];
        sbias[tid] = bias[tid];
    }
    const short* Ab = (const short*)A;
    floatx4 acc[3];
#pragma unroll
    for (int j = 0; j < 3; ++j) acc[j] = (floatx4){0.f, 0.f, 0.f, 0.f};

    short8 aR = {0,0,0,0,0,0,0,0};
    short8 wR[3];
    if (tid < 64) aR = *(const short8*)&Ab[(size_t)(m0 + (tid >> 2)) * K + kc];
#pragma unroll
    for (int j = 0; j < 3; ++j)
        wR[j] = *(const short8*)&Wb[(size_t)(wrow + 64 * j) * K + kc];

    for (int k0 = 0; k0 < K; k0 += 32) {
        if (tid < 64) *(short8*)&As[(tid >> 2) * LDA + kc] = aR;
#pragma unroll
        for (int j = 0; j < 3; ++j)
            *(short8*)&Ws[(wrow + 64 * j) * LDA + kc] = wR[j];
        __syncthreads();
        int kn = k0 + 32;
        if (kn < K) {
            if (tid < 64) aR = *(const short8*)&Ab[(size_t)(m0 + (tid >> 2)) * K + kn + kc];
#pragma unroll
            for (int j = 0; j < 3; ++j)
                wR[j] = *(const short8*)&Wb[(size_t)(wrow + 64 * j) * K + kn + kc];
        }
        short8 af = *(const short8*)&As[fm * LDA + q * 8];
#pragma unroll
        for (int j = 0; j < 3; ++j) {
            int ct = wv * 3 + j;
            short8 bf = *(const short8*)&Ws[(ct * 16 + fm) * LDA + q * 8];
            acc[j] = __builtin_amdgcn_mfma_f32_16x16x32_bf16(af, bf, acc[j], 0, 0, 0);
        }
        __syncthreads();
    }

    float v[3][4];
#pragma unroll
    for (int r = 0; r < 4; ++r) {
#pragma unroll
        for (int j = 0; j < 3; ++j) {
            int col = (wv * 3 + j) * 16 + fm;
            v[j][r] = acc[j][r] + sbias[col];
        }
    }
#pragma unroll
    for (int r = 0; r < 4; ++r) {
        int m = m0 + q * 4 + r;
#pragma unroll
        for (int j = 0; j < 3; ++j)
            residual[(size_t)m * DMODEL + (wv * 3 + j) * 16 + fm] = v[j][r];
    }
#pragma unroll
    for (int r = 0; r < 4; ++r) {
        float s1 = v[0][r] + v[1][r] + v[2][r];
        float s2 = v[0][r]*v[0][r] + v[1][r]*v[1][r] + v[2][r]*v[2][r];
        s1 += __shfl_xor(s1, 1); s2 += __shfl_xor(s2, 1);
        s1 += __shfl_xor(s1, 2); s2 += __shfl_xor(s2, 2);
        s1 += __shfl_xor(s1, 4); s2 += __shfl_xor(s2, 4);
        s1 += __shfl_xor(s1, 8); s2 += __shfl_xor(s2, 8);
        if (fm == 0) { sS1[wv][q * 4 + r] = s1; sS2[wv][q * 4 + r] = s2; }
    }
    __syncthreads();
#pragma unroll
    for (int r = 0; r < 4; ++r) {
        int row = q * 4 + r;
        int m = m0 + row;
        float S1 = sS1[0][row] + sS1[1][row] + sS1[2][row] + sS1[3][row];
        float S2 = sS2[0][row] + sS2[1][row] + sS2[2][row] + sS2[3][row];
        float mean = S1 * (1.f / DMODEL);
        float var  = S2 * (1.f / DMODEL) - mean * mean;
        float rstd = rsqrtf(var + 1e-5f);
#pragma unroll
        for (int j = 0; j < 3; ++j) {
            int col = (wv * 3 + j) * 16 + fm;
            float o = (v[j][r] - mean) * rstd * slw[col] + slb[col];
            hn[(size_t)m * DMODEL + col] = __float2bfloat16(o);
        }
    }
}

// ---------------- cooperative mega-kernel: 24 layers, 4 stages each ----------------
// LDS union offsets (bytes):
//  gemm_in: As@0 (5120), Ws@5120 (5120)
//  conv:    su@0 (4x97x4=1552), sx@1552 (176)
//  scan:    sdt@0, su_@3136, sz_@6272, sB_@9408, sC_@12544, sprod@15680 (49x272x4)
//  gemm_ln: As@0 (1280), Ws@1280 (15360), slw@16640, slb@17408, sS1@18176, sS2@18432
#define SM_BYTES 68992
__global__ __launch_bounds__(256) void mamba_mega(
    __hip_bfloat16* __restrict__ hn, float* __restrict__ xz,
    float* __restrict__ ubuf, float* __restrict__ dtbuf, float* __restrict__ bcbuf,
    __hip_bfloat16* __restrict__ ybf, float* __restrict__ residual,
    const short* __restrict__ w_in, const short* __restrict__ w_out,
    const float* __restrict__ conv_w, const float* __restrict__ conv_b,
    const float* __restrict__ xproj_w,
    const float* __restrict__ dtw_all, const float* __restrict__ dtb_all,
    const float* __restrict__ A_log, const float* __restrict__ D_param,
    const float* __restrict__ norm_w, const float* __restrict__ norm_b,
    const float* __restrict__ normf_w, const float* __restrict__ normf_b,
    float* __restrict__ outp)
{
    __shared__ __align__(16) char sm[SM_BYTES];
    cg::grid_group grid = cg::this_grid();
    int bid = blockIdx.x;
    int tid = threadIdx.x;
    int wv = tid >> 6, lane = tid & 63;
    int fm = lane & 15, q = lane >> 4;
    int row = tid >> 2, kc = (tid & 3) * 8;

    for (int layer = 0; layer < DEPTH; ++layer) {
        // ===== stage 1: in_proj GEMM: xz[1568,768] = hn @ Wi^T =====
        {
            const short* Wi = w_in + (size_t)layer * 768 * DMODEL;
            short* As = (short*)sm;
            short* Ws = (short*)(sm + 5120);
            const short* Ab = (const short*)hn;
            for (int vt = bid; vt < 300; vt += 256) {
                int m0 = (vt % 25) * 64, n0 = (vt / 25) * 64;
                floatx4 acc[4];
#pragma unroll
                for (int nt = 0; nt < 4; ++nt) acc[nt] = (floatx4){0.f,0.f,0.f,0.f};
#pragma unroll
                for (int k0 = 0; k0 < DMODEL; k0 += 32) {
                    int m = m0 + row;
                    short8 v = {0,0,0,0,0,0,0,0};
                    if (m < NTOK) v = *(const short8*)&Ab[(size_t)m * DMODEL + k0 + kc];
                    *(short8*)&As[row * LDA + kc] = v;
                    short8 w = *(const short8*)&Wi[(size_t)(n0 + row) * DMODEL + k0 + kc];
                    *(short8*)&Ws[row * LDA + kc] = w;
                    __syncthreads();
                    short8 af = *(const short8*)&As[(wv * 16 + fm) * LDA + q * 8];
#pragma unroll
                    for (int nt = 0; nt < 4; ++nt) {
                        short8 bf = *(const short8*)&Ws[(nt * 16 + fm) * LDA + q * 8];
                        acc[nt] = __builtin_amdgcn_mfma_f32_16x16x32_bf16(af, bf, acc[nt], 0, 0, 0);
                    }
                    __syncthreads();
                }
#pragma unroll
                for (int nt = 0; nt < 4; ++nt) {
                    int col = n0 + nt * 16 + fm;
#pragma unroll
                    for (int r = 0; r < 4; ++r) {
                        int mrow = m0 + wv * 16 + q * 4 + r;
                        if (mrow < NTOK) xz[(size_t)mrow * 768 + col] = acc[nt][r];
                    }
                }
            }
        }
        __threadfence();
        grid.sync();

        // ===== stage 2: conv + silu + x_proj + dt =====
        {
            const float* cw  = conv_w + (size_t)layer * DINNER * 4;
            const float* cb  = conv_b + (size_t)layer * DINNER;
            const float* xpw = xproj_w + (size_t)layer * 44 * DINNER;
            const float* dtw = dtw_all + (size_t)layer * DINNER * DTRANK;
            const float* dtb = dtb_all + (size_t)layer * DINNER;
            float (*su)[97] = (float(*)[97])sm;
            float* sx = (float*)(sm + 1552);
            for (int blk = bid; blk < NTOK; blk += 256) {
                int b = blk / LSEQ, l = blk % LSEQ;
                for (int d = tid; d < DINNER; d += 256) {
                    float acc = cb[d];
                    float4 w4 = *(const float4*)&cw[d * 4];
                    int li = l - 3;
                    if (li >= 0)     acc += xz[(size_t)(b * LSEQ + li    ) * 768 + d] * w4.x;
                    if (li + 1 >= 0) acc += xz[(size_t)(b * LSEQ + li + 1) * 768 + d] * w4.y;
                    if (li + 2 >= 0) acc += xz[(size_t)(b * LSEQ + li + 2) * 768 + d] * w4.z;
                    acc += xz[(size_t)(b * LSEQ + l) * 768 + d] * w4.w;
                    float sig = 1.f / (1.f + __expf(-acc));
                    float val = acc * sig;
                    su[d / 96][d % 96] = val;
                    ubuf[(size_t)(b * LSEQ + l) * DINNER + d] = val;
                }
                __syncthreads();
                if (tid < 176) {
                    int e = tid >> 2, p = tid & 3;
                    float acc = 0.f;
                    const float* wr = &xpw[e * DINNER + p * 96];
                    const float* ur = &su[p][0];
#pragma unroll 8
                    for (int j = 0; j < 96; ++j) acc += ur[j] * wr[j];
                    acc += __shfl_xor(acc, 1);
                    acc += __shfl_xor(acc, 2);
                    if (p == 0) sx[e] = acc;
                }
                __syncthreads();
                for (int d = tid; d < DINNER; d += 256) {
                    float acc = dtb[d];
#pragma unroll
                    for (int r = 0; r < DTRANK; ++r) acc += sx[r] * dtw[d * DTRANK + r];
                    float sp = (acc > 20.f) ? acc : log1pf(__expf(acc));
                    dtbuf[(size_t)(b * LSEQ + l) * DINNER + d] = sp;
                }
                if (tid < 32) bcbuf[(size_t)(b * LSEQ + l) * 32 + tid] = sx[DTRANK + tid];
                __syncthreads();   // su/sx reused next virtual block
            }
        }
        __threadfence();
        grid.sync();

        // ===== stage 3: selective scan + gating =====
        if (bid < 192) {
            const float* Alog = A_log + (size_t)layer * DINNER * DSTATE;
            const float* Dp   = D_param + (size_t)layer * DINNER;
            float* sdt = (float*)sm;
            float* su_ = (float*)(sm + 3136);
            float* sz_ = (float*)(sm + 6272);
            float* sB_ = (float*)(sm + 9408);
            float* sC_ = (float*)(sm + 12544);
            float* sprod = (float*)(sm + 15680);
            int b = bid / 24, dg = bid % 24;
            int s = tid & 15, dl = tid >> 4;
            int d = dg * 16 + dl;
            float Ads = -expf(Alog[d * DSTATE + s]);
            float Dd2 = Dp[dg * 16 + (tid & 15)];
            float h = 0.f;
            for (int c0 = 0; c0 < LSEQ; c0 += TCH) {
                if (tid < TCH * 4) {
                    int t = tid >> 2, j4 = (tid & 3) * 4;
                    size_t tok = (size_t)(b * LSEQ + c0 + t);
                    *(float4*)&sdt[t * 16 + j4] = *(const float4*)&dtbuf[tok * DINNER + dg * 16 + j4];
                    *(float4*)&su_[t * 16 + j4] = *(const float4*)&ubuf [tok * DINNER + dg * 16 + j4];
                    *(float4*)&sz_[t * 16 + j4] = *(const float4*)&xz   [tok * 768 + DINNER + dg * 16 + j4];
                    *(float4*)&sB_[t * 16 + j4] = *(const float4*)&bcbuf[tok * 32 + j4];
                    *(float4*)&sC_[t * 16 + j4] = *(const float4*)&bcbuf[tok * 32 + 16 + j4];
                }
                __syncthreads();
#pragma unroll 7
                for (int t = 0; t < TCH; ++t) {
                    float dtv = sdt[t * 16 + dl];
                    float uv  = su_[t * 16 + dl];
                    float Bv  = sB_[t * 16 + s];
                    float Cv  = sC_[t * 16 + s];
                    float dA  = __expf(dtv * Ads);
                    h = dA * h + (dtv * uv) * Bv;
                    sprod[t * 272 + dl * 17 + s] = h * Cv;
                }
                __syncthreads();
                for (int i = tid; i < TCH * 16; i += 256) {
                    int t = i >> 4, dl2 = i & 15;
                    float sum = 0.f;
#pragma unroll
                    for (int j = 0; j < 16; ++j) sum += sprod[t * 272 + dl2 * 17 + j];
                    float uv = su_[t * 16 + dl2];
                    float zv = sz_[t * 16 + dl2];
                    float sig = 1.f / (1.f + __expf(-zv));
                    ybf[(size_t)(b * LSEQ + c0 + t) * DINNER + dg * 16 + dl2] =
                        __float2bfloat16((sum + uv * Dd2) * (zv * sig));
                }
                __syncthreads();
            }
        }
        __threadfence();
        grid.sync();

        // ===== stage 4: out_proj GEMM + residual + LN =====
        if (bid < 98) {
            const short* Wo = w_out + (size_t)layer * DMODEL * DINNER;
            int last = (layer == DEPTH - 1);
            const float* lnw = last ? normf_w : norm_w + (layer + 1) * DMODEL;
            const float* lnb = last ? normf_b : norm_b + (layer + 1) * DMODEL;
            short* As = (short*)sm;
            short* Ws = (short*)(sm + 1280);
            float* slw = (float*)(sm + 16640);
            float* slb = (float*)(sm + 17408);
            float* sS1 = (float*)(sm + 18176);   // [4][16]
            float* sS2 = (float*)(sm + 18432);
            int m0 = bid * 16;
            int wrow = tid >> 2;
            if (tid < 192) { slw[tid] = lnw[tid]; slb[tid] = lnb[tid]; }
            const short* Ab = (const short*)ybf;
            floatx4 acc[3];
#pragma unroll
            for (int j = 0; j < 3; ++j) acc[j] = (floatx4){0.f, 0.f, 0.f, 0.f};
            short8 aR = {0,0,0,0,0,0,0,0};
            short8 wR[3];
            if (tid < 64) aR = *(const short8*)&Ab[(size_t)(m0 + (tid >> 2)) * DINNER + kc];
#pragma unroll
            for (int j = 0; j < 3; ++j)
                wR[j] = *(const short8*)&Wo[(size_t)(wrow + 64 * j) * DINNER + kc];
            for (int k0 = 0; k0 < DINNER; k0 += 32) {
                if (tid < 64) *(short8*)&As[(tid >> 2) * LDA + kc] = aR;
#pragma unroll
                for (int j = 0; j < 3; ++j)
                    *(short8*)&Ws[(wrow + 64 * j) * LDA + kc] = wR[j];
                __syncthreads();
                int kn = k0 + 32;
                if (kn < DINNER) {
                    if (tid < 64) aR = *(const short8*)&Ab[(size_t)(m0 + (tid >> 2)) * DINNER + kn + kc];
#pragma unroll
                    for (int j = 0; j < 3; ++j)
                        wR[j] = *(const short8*)&Wo[(size_t)(wrow + 64 * j) * DINNER + kn + kc];
                }
                short8 af = *(const short8*)&As[fm * LDA + q * 8];
#pragma unroll
                for (int j = 0; j < 3; ++j) {
                    int ct = wv * 3 + j;
                    short8 bf = *(const short8*)&Ws[(ct * 16 + fm) * LDA + q * 8];
                    acc[j] = __builtin_amdgcn_mfma_f32_16x16x32_bf16(af, bf, acc[j], 0, 0, 0);
                }
                __syncthreads();
            }
            float v[3][4];
#pragma unroll
            for (int r = 0; r < 4; ++r) {
                int m = m0 + q * 4 + r;
#pragma unroll
                for (int j = 0; j < 3; ++j) {
                    int col = (wv * 3 + j) * 16 + fm;
                    v[j][r] = acc[j][r] + residual[(size_t)m * DMODEL + col];
                }
            }
#pragma unroll
            for (int r = 0; r < 4; ++r) {
                int m = m0 + q * 4 + r;
#pragma unroll
                for (int j = 0; j < 3; ++j)
                    residual[(size_t)m * DMODEL + (wv * 3 + j) * 16 + fm] = v[j][r];
            }
#pragma unroll
            for (int r = 0; r < 4; ++r) {
                float s1 = v[0][r] + v[1][r] + v[2][r];
                float s2 = v[0][r]*v[0][r] + v[1][r]*v[1][r] + v[2][r]*v[2][r];
                s1 += __shfl_xor(s1, 1); s2 += __shfl_xor(s2, 1);
                s1 += __shfl_xor(s1, 2); s2 += __shfl_xor(s2, 2);
                s1 += __shfl_xor(s1, 4); s2 += __shfl_xor(s2, 4);
                s1 += __shfl_xor(s1, 8); s2 += __shfl_xor(s2, 8);
                if (fm == 0) { sS1[wv * 16 + q * 4 + r] = s1; sS2[wv * 16 + q * 4 + r] = s2; }
            }
            __syncthreads();
#pragma unroll
            for (int r = 0; r < 4; ++r) {
                int rr = q * 4 + r;
                int m = m0 + rr;
                float S1 = sS1[rr] + sS1[16 + rr] + sS1[32 + rr] + sS1[48 + rr];
                float S2 = sS2[rr] + sS2[16 + rr] + sS2[32 + rr] + sS2[48 + rr];
                float mean = S1 * (1.f / DMODEL);
                float var  = S2 * (1.f / DMODEL) - mean * mean;
                float rstd = rsqrtf(var + 1e-5f);
#pragma unroll
                for (int j = 0; j < 3; ++j) {
                    int col = (wv * 3 + j) * 16 + fm;
                    float o = (v[j][r] - mean) * rstd * slw[col] + slb[col];
                    if (last) outp[(size_t)m * DMODEL + col] = o;
                    else      hn[(size_t)m * DMODEL + col] = __float2bfloat16(o);
                }
            }
        }
        __threadfence();
        grid.sync();
    }
}

// ---------------------------------------------------------------------------
extern "C" void kernel_launch(void* const* d_in, const int* in_sizes, int n_in,
                              void* d_out, int out_size, void* d_ws, size_t ws_size,
                              hipStream_t stream)
{
    const float* x         = (const float*)d_in[0];
    const float* pe_w      = (const float*)d_in[1];
    const float* pe_b      = (const float*)d_in[2];
    const float* norm_w    = (const float*)d_in[3];
    const float* norm_b    = (const float*)d_in[4];
    const float* in_proj_w = (const float*)d_in[5];
    const float* conv_w    = (const float*)d_in[6];
    const float* conv_b    = (const float*)d_in[7];
    const float* xproj_w   = (const float*)d_in[8];
    const float* dtproj_w  = (const float*)d_in[9];
    const float* dtproj_b  = (const float*)d_in[10];
    const float* A_log     = (const float*)d_in[11];
    const float* D_param   = (const float*)d_in[12];
    const float* outproj_w = (const float*)d_in[13];
    const float* normf_w   = (const float*)d_in[14];
    const float* normf_b   = (const float*)d_in[15];

    float* ws = (float*)d_ws;
    float* residual = ws;                       // 301056 f32
    float* xz       = residual + 301056;        // 1204224 f32
    float* ubuf     = xz + 1204224;             // 602112 f32
    float* dtbuf    = ubuf + 602112;            // 602112 f32
    float* bcbuf    = dtbuf + 602112;           // 50176 f32
    __hip_bfloat16* hn      = (__hip_bfloat16*)(ws + 2759680);  // 301056 bf16
    __hip_bfloat16* ybf     = (__hip_bfloat16*)(ws + 2910208);  // 602112 bf16
    __hip_bfloat16* patches = (__hip_bfloat16*)(ws + 3211264);  // 1204224 bf16
    short* w_in  = (short*)(ws + 3813376);      // 3538944 bf16
    short* w_out = (short*)(ws + 5582848);      // 1769472 bf16
    short* w_pe  = (short*)(ws + 6467584);      // 147456 bf16
    float* outp  = (float*)d_out;

    cvt_weights<<<5328, 256, 0, stream>>>(
        in_proj_w, outproj_w, pe_w, w_in, w_out, w_pe);
    im2col<<<4704, 256, 0, stream>>>(x, patches);
    gemm_ln_pe<768><<<98, 256, 0, stream>>>(
        patches, w_pe, pe_b, residual, hn, norm_w, norm_b);

    void* kargs[] = {
        (void*)&hn, (void*)&xz, (void*)&ubuf, (void*)&dtbuf, (void*)&bcbuf,
        (void*)&ybf, (void*)&residual, (void*)&w_in, (void*)&w_out,
        (void*)&conv_w, (void*)&conv_b, (void*)&xproj_w,
        (void*)&dtproj_w, (void*)&dtproj_b, (void*)&A_log, (void*)&D_param,
        (void*)&norm_w, (void*)&norm_b, (void*)&normf_w, (void*)&normf_b,
        (void*)&outp
    };
    hipLaunchCooperativeKernel(reinterpret_cast<void*>(mamba_mega),
                               dim3(256), dim3(256), kargs, 0, stream);
}

// Round 10
// 1661.861 us; speedup vs baseline: 4.1840x; 4.1840x over previous
//
#include <hip/hip_runtime.h>
#include <hip/hip_bf16.h>

// ---------------------------------------------------------------------------
// VisionMamba, round 9: revert mega-kernel; fuse out_proj+LN+in_proj instead.
// B=8, L=196, D_MODEL=192, D_INNER=384, D_STATE=16, DT_RANK=12, DEPTH=24.
//
// R9: R8's grid.sync() cost ~60-70us each (cross-XCD L2 flush: FETCH_SIZE
// 407MB/dispatch) — persistent-grid sync is a dead end on gfx950. Back to
// R7 dispatch structure (1465us) with a sync-free fusion: one kernel does
// out_proj(i) + residual + LN(i+1) + in_proj(i+1). LN result stays in a
// 16x200 bf16 LDS tile (A of the next GEMM); in_proj W staged per k-step in
// a 49KB XOR-swizzled LDS tile (rows 32 shorts, chunk c^((row>>1)&3) ->
// 16B-aligned b128, <=2-way banks). 4->3 kernels/layer; 99->76 dispatches.
// ---------------------------------------------------------------------------

#define NTOK   1568   // B * L
#define DMODEL 192
#define DINNER 384
#define DSTATE 16
#define DTRANK 12
#define DEPTH  24
#define LSEQ   196
#define TCH    49     // scan time-chunk (196 = 4*49)
#define LDA    40     // LDS row stride in bf16 elements (80B)

typedef __attribute__((ext_vector_type(8))) short short8;
typedef __attribute__((ext_vector_type(4))) short short4v;
typedef __attribute__((ext_vector_type(4))) float floatx4;

__device__ inline short f2bf(float f) {
    __hip_bfloat16 h = __float2bfloat16(f);
    return *reinterpret_cast<short*>(&h);
}

// ---------------- weight fp32 -> bf16 conversion (in/out/pe) ----------------
#define CVT_N1 884736   // in_proj  24*768*192 /4
#define CVT_N2 442368   // out_proj 24*192*384 /4
#define CVT_N3 36864    // pe       192*768    /4
__global__ __launch_bounds__(256) void cvt_weights(
    const float* __restrict__ inw, const float* __restrict__ outw,
    const float* __restrict__ pew,
    short* __restrict__ w_in, short* __restrict__ w_out,
    short* __restrict__ w_pe)
{
    int idx = blockIdx.x * 256 + threadIdx.x;
    float4 v;
    short* dst;
    if (idx < CVT_N1) {
        v = ((const float4*)inw)[idx]; dst = w_in + (size_t)idx * 4;
    } else if (idx < CVT_N1 + CVT_N2) {
        int i = idx - CVT_N1;
        v = ((const float4*)outw)[i]; dst = w_out + (size_t)i * 4;
    } else if (idx < CVT_N1 + CVT_N2 + CVT_N3) {
        int i = idx - CVT_N1 - CVT_N2;
        v = ((const float4*)pew)[i]; dst = w_pe + (size_t)i * 4;
    } else {
        return;
    }
    short4v o;
    o[0] = f2bf(v.x); o[1] = f2bf(v.y); o[2] = f2bf(v.z); o[3] = f2bf(v.w);
    *(short4v*)dst = o;
}

// ---------------- im2col for patch embed (bf16 out) ----------------
__global__ __launch_bounds__(256) void im2col(
    const float* __restrict__ x, __hip_bfloat16* __restrict__ patches)
{
    int idx = blockIdx.x * 256 + threadIdx.x;
    if (idx >= NTOK * 768) return;
    int tok = idx / 768, e = idx % 768;
    int b = tok / LSEQ, l = tok % LSEQ;
    int py = l / 14, px = l % 14;
    int ic = e >> 8, rem = e & 255, ky = rem >> 4, kx = rem & 15;
    patches[idx] = __float2bfloat16(x[((b * 3 + ic) * 224 + py * 16 + ky) * 224 + px * 16 + kx]);
}

// ---------------- patch-embed GEMM + LN -> residual, hn (R7 gemm_ln, K=768) ----------------
template<int K>
__global__ __launch_bounds__(256) void gemm_ln_pe(
    const __hip_bfloat16* __restrict__ A, const short* __restrict__ Wb,
    const float* __restrict__ bias, float* __restrict__ residual,
    __hip_bfloat16* __restrict__ hn,
    const float* __restrict__ lnw, const float* __restrict__ lnb)
{
    __shared__ short As[16 * LDA];
    __shared__ short Ws[192 * LDA];
    __shared__ float slw[192], slb[192], sbias[192];
    __shared__ float sS1[4][16], sS2[4][16];
    int tid = threadIdx.x;
    int m0 = blockIdx.x * 16;
    int wv = tid >> 6, lane = tid & 63;
    int fm = lane & 15, q = lane >> 4;
    int wrow = tid >> 2, kc = (tid & 3) * 8;
    if (tid < 192) {
        slw[tid] = lnw[tid];
        slb[tid] = lnb[tid];
        sbias[tid] = bias[tid];
    }
    const short* Ab = (const short*)A;
    floatx4 acc[3];
#pragma unroll
    for (int j = 0; j < 3; ++j) acc[j] = (floatx4){0.f, 0.f, 0.f, 0.f};

    short8 aR = {0,0,0,0,0,0,0,0};
    short8 wR[3];
    if (tid < 64) aR = *(const short8*)&Ab[(size_t)(m0 + (tid >> 2)) * K + kc];
#pragma unroll
    for (int j = 0; j < 3; ++j)
        wR[j] = *(const short8*)&Wb[(size_t)(wrow + 64 * j) * K + kc];

    for (int k0 = 0; k0 < K; k0 += 32) {
        if (tid < 64) *(short8*)&As[(tid >> 2) * LDA + kc] = aR;
#pragma unroll
        for (int j = 0; j < 3; ++j)
            *(short8*)&Ws[(wrow + 64 * j) * LDA + kc] = wR[j];
        __syncthreads();
        int kn = k0 + 32;
        if (kn < K) {
            if (tid < 64) aR = *(const short8*)&Ab[(size_t)(m0 + (tid >> 2)) * K + kn + kc];
#pragma unroll
            for (int j = 0; j < 3; ++j)
                wR[j] = *(const short8*)&Wb[(size_t)(wrow + 64 * j) * K + kn + kc];
        }
        short8 af = *(const short8*)&As[fm * LDA + q * 8];
#pragma unroll
        for (int j = 0; j < 3; ++j) {
            int ct = wv * 3 + j;
            short8 bf = *(const short8*)&Ws[(ct * 16 + fm) * LDA + q * 8];
            acc[j] = __builtin_amdgcn_mfma_f32_16x16x32_bf16(af, bf, acc[j], 0, 0, 0);
        }
        __syncthreads();
    }

    float v[3][4];
#pragma unroll
    for (int r = 0; r < 4; ++r)
#pragma unroll
        for (int j = 0; j < 3; ++j)
            v[j][r] = acc[j][r] + sbias[(wv * 3 + j) * 16 + fm];
#pragma unroll
    for (int r = 0; r < 4; ++r) {
        int m = m0 + q * 4 + r;
#pragma unroll
        for (int j = 0; j < 3; ++j)
            residual[(size_t)m * DMODEL + (wv * 3 + j) * 16 + fm] = v[j][r];
    }
#pragma unroll
    for (int r = 0; r < 4; ++r) {
        float s1 = v[0][r] + v[1][r] + v[2][r];
        float s2 = v[0][r]*v[0][r] + v[1][r]*v[1][r] + v[2][r]*v[2][r];
        s1 += __shfl_xor(s1, 1); s2 += __shfl_xor(s2, 1);
        s1 += __shfl_xor(s1, 2); s2 += __shfl_xor(s2, 2);
        s1 += __shfl_xor(s1, 4); s2 += __shfl_xor(s2, 4);
        s1 += __shfl_xor(s1, 8); s2 += __shfl_xor(s2, 8);
        if (fm == 0) { sS1[wv][q * 4 + r] = s1; sS2[wv][q * 4 + r] = s2; }
    }
    __syncthreads();
#pragma unroll
    for (int r = 0; r < 4; ++r) {
        int row = q * 4 + r;
        int m = m0 + row;
        float S1 = sS1[0][row] + sS1[1][row] + sS1[2][row] + sS1[3][row];
        float S2 = sS2[0][row] + sS2[1][row] + sS2[2][row] + sS2[3][row];
        float mean = S1 * (1.f / DMODEL);
        float var  = S2 * (1.f / DMODEL) - mean * mean;
        float rstd = rsqrtf(var + 1e-5f);
#pragma unroll
        for (int j = 0; j < 3; ++j) {
            int col = (wv * 3 + j) * 16 + fm;
            float o = (v[j][r] - mean) * rstd * slw[col] + slb[col];
            hn[(size_t)m * DMODEL + col] = __float2bfloat16(o);
        }
    }
}

// ---------------- gemm_in (layer 0 only): xz = hn @ W^T, K=192 ----------------
template<int K>
__global__ __launch_bounds__(256) void gemm_in(
    const __hip_bfloat16* __restrict__ A, const short* __restrict__ Wb,
    float* __restrict__ C, int M, int N)
{
    __shared__ short As[64 * LDA];
    __shared__ short Ws[64 * LDA];
    int tid = threadIdx.x;
    int m0 = blockIdx.x * 64, n0 = blockIdx.y * 64;
    int wv = tid >> 6, lane = tid & 63;
    int fm = lane & 15, q = lane >> 4;
    int row = tid >> 2, kc = (tid & 3) * 8;
    const short* Ab = (const short*)A;
    floatx4 acc[4];
#pragma unroll
    for (int nt = 0; nt < 4; ++nt) acc[nt] = (floatx4){0.f, 0.f, 0.f, 0.f};

#pragma unroll
    for (int k0 = 0; k0 < K; k0 += 32) {
        {
            int m = m0 + row;
            short8 v = {0,0,0,0,0,0,0,0};
            if (m < M) v = *(const short8*)&Ab[(size_t)m * K + k0 + kc];
            *(short8*)&As[row * LDA + kc] = v;
        }
        {
            short8 w = *(const short8*)&Wb[(size_t)(n0 + row) * K + k0 + kc];
            *(short8*)&Ws[row * LDA + kc] = w;
        }
        __syncthreads();
        short8 af = *(const short8*)&As[(wv * 16 + fm) * LDA + q * 8];
#pragma unroll
        for (int nt = 0; nt < 4; ++nt) {
            short8 bf = *(const short8*)&Ws[(nt * 16 + fm) * LDA + q * 8];
            acc[nt] = __builtin_amdgcn_mfma_f32_16x16x32_bf16(af, bf, acc[nt], 0, 0, 0);
        }
        __syncthreads();
    }
#pragma unroll
    for (int nt = 0; nt < 4; ++nt) {
        int col = n0 + nt * 16 + fm;
#pragma unroll
        for (int r = 0; r < 4; ++r) {
            int mrow = m0 + wv * 16 + q * 4 + r;
            if (mrow < M) C[(size_t)mrow * N + col] = acc[nt][r];
        }
    }
}

// ---------------- fused: out_proj(i) + residual + LN(i+1) + in_proj(i+1) ----------------
// grid 98 x 256. Phase A = R7 gemm_ln<384> (no bias). LN result -> hnT LDS
// (16 x stride-200 bf16). Phase C: xz[16 rows, 768 cols], K=192; W staged
// per k-step into Ws2 (768 rows x 32 shorts, chunk-XOR swizzle).
__global__ __launch_bounds__(256) void fused_oln_in(
    const __hip_bfloat16* __restrict__ ybf, const short* __restrict__ Wo,
    const short* __restrict__ Wi, float* __restrict__ residual,
    float* __restrict__ xz, float* __restrict__ outf,
    const float* __restrict__ lnw, const float* __restrict__ lnb)
{
    __shared__ __align__(16) char sm[55552];
    short* hnT = (short*)sm;                 // 16 x 200 shorts (6400 B)
    short* As  = (short*)(sm + 6400);        // 16 x LDA
    short* Ws  = (short*)(sm + 7680);        // 192 x LDA (ends 23040)
    float* slw = (float*)(sm + 23040);       // 192 f
    float* slb = (float*)(sm + 23808);       // 192 f
    float* sS1 = (float*)(sm + 24576);       // 64 f
    float* sS2 = (float*)(sm + 24832);       // 64 f
    short* Ws2 = (short*)(sm + 6400);        // 768 x 32 shorts (49152 B, phase C)

    int tid = threadIdx.x;
    int m0 = blockIdx.x * 16;
    int wv = tid >> 6, lane = tid & 63;
    int fm = lane & 15, q = lane >> 4;
    int wrow = tid >> 2, kc = (tid & 3) * 8;
    if (tid < 192) { slw[tid] = lnw[tid]; slb[tid] = lnb[tid]; }

    // ===== phase A: out_proj K=384 =====
    const short* Ab = (const short*)ybf;
    floatx4 acc[3];
#pragma unroll
    for (int j = 0; j < 3; ++j) acc[j] = (floatx4){0.f, 0.f, 0.f, 0.f};
    short8 aR = {0,0,0,0,0,0,0,0};
    short8 wR[3];
    if (tid < 64) aR = *(const short8*)&Ab[(size_t)(m0 + (tid >> 2)) * DINNER + kc];
#pragma unroll
    for (int j = 0; j < 3; ++j)
        wR[j] = *(const short8*)&Wo[(size_t)(wrow + 64 * j) * DINNER + kc];

    for (int k0 = 0; k0 < DINNER; k0 += 32) {
        if (tid < 64) *(short8*)&As[(tid >> 2) * LDA + kc] = aR;
#pragma unroll
        for (int j = 0; j < 3; ++j)
            *(short8*)&Ws[(wrow + 64 * j) * LDA + kc] = wR[j];
        __syncthreads();
        int kn = k0 + 32;
        if (kn < DINNER) {
            if (tid < 64) aR = *(const short8*)&Ab[(size_t)(m0 + (tid >> 2)) * DINNER + kn + kc];
#pragma unroll
            for (int j = 0; j < 3; ++j)
                wR[j] = *(const short8*)&Wo[(size_t)(wrow + 64 * j) * DINNER + kn + kc];
        }
        short8 af = *(const short8*)&As[fm * LDA + q * 8];
#pragma unroll
        for (int j = 0; j < 3; ++j) {
            int ct = wv * 3 + j;
            short8 bf = *(const short8*)&Ws[(ct * 16 + fm) * LDA + q * 8];
            acc[j] = __builtin_amdgcn_mfma_f32_16x16x32_bf16(af, bf, acc[j], 0, 0, 0);
        }
        __syncthreads();
    }

    // ===== phase B: residual += C; LN -> hnT (or d_out) =====
    float v[3][4];
#pragma unroll
    for (int r = 0; r < 4; ++r) {
        int m = m0 + q * 4 + r;
#pragma unroll
        for (int j = 0; j < 3; ++j) {
            int col = (wv * 3 + j) * 16 + fm;
            v[j][r] = acc[j][r] + residual[(size_t)m * DMODEL + col];
        }
    }
#pragma unroll
    for (int r = 0; r < 4; ++r) {
        int m = m0 + q * 4 + r;
#pragma unroll
        for (int j = 0; j < 3; ++j)
            residual[(size_t)m * DMODEL + (wv * 3 + j) * 16 + fm] = v[j][r];
    }
#pragma unroll
    for (int r = 0; r < 4; ++r) {
        float s1 = v[0][r] + v[1][r] + v[2][r];
        float s2 = v[0][r]*v[0][r] + v[1][r]*v[1][r] + v[2][r]*v[2][r];
        s1 += __shfl_xor(s1, 1); s2 += __shfl_xor(s2, 1);
        s1 += __shfl_xor(s1, 2); s2 += __shfl_xor(s2, 2);
        s1 += __shfl_xor(s1, 4); s2 += __shfl_xor(s2, 4);
        s1 += __shfl_xor(s1, 8); s2 += __shfl_xor(s2, 8);
        if (fm == 0) { sS1[wv * 16 + q * 4 + r] = s1; sS2[wv * 16 + q * 4 + r] = s2; }
    }
    __syncthreads();
#pragma unroll
    for (int r = 0; r < 4; ++r) {
        int row = q * 4 + r;
        int m = m0 + row;
        float S1 = sS1[row] + sS1[16 + row] + sS1[32 + row] + sS1[48 + row];
        float S2 = sS2[row] + sS2[16 + row] + sS2[32 + row] + sS2[48 + row];
        float mean = S1 * (1.f / DMODEL);
        float var  = S2 * (1.f / DMODEL) - mean * mean;
        float rstd = rsqrtf(var + 1e-5f);
#pragma unroll
        for (int j = 0; j < 3; ++j) {
            int col = (wv * 3 + j) * 16 + fm;
            float o = (v[j][r] - mean) * rstd * slw[col] + slb[col];
            if (outf) outf[(size_t)m * DMODEL + col] = o;
            else      hnT[row * 200 + col] = f2bf(o);
        }
    }
    if (outf) return;   // final layer: no next in_proj
    __syncthreads();    // hnT complete; stats/slw regions now dead

    // ===== phase C: in_proj(i+1): xz[m0..m0+16, 0..768), K=192 =====
    floatx4 acc2[12];
#pragma unroll
    for (int j = 0; j < 12; ++j) acc2[j] = (floatx4){0.f, 0.f, 0.f, 0.f};
#pragma unroll
    for (int k0 = 0; k0 < DMODEL; k0 += 32) {
        // stage W slice: 768 rows x 32 shorts, chunk-XOR swizzle
        for (int idx = tid; idx < 3072; idx += 256) {
            int rown = idx >> 2, c = idx & 3;
            short8 w = *(const short8*)&Wi[(size_t)rown * DMODEL + k0 + c * 8];
            *(short8*)&Ws2[rown * 32 + ((c ^ ((rown >> 1) & 3)) * 8)] = w;
        }
        __syncthreads();
        short8 af = *(const short8*)&hnT[fm * 200 + k0 + q * 8];
#pragma unroll
        for (int j = 0; j < 12; ++j) {
            int n = (wv * 12 + j) * 16 + fm;
            short8 bf = *(const short8*)&Ws2[n * 32 + ((q ^ ((n >> 1) & 3)) * 8)];
            acc2[j] = __builtin_amdgcn_mfma_f32_16x16x32_bf16(af, bf, acc2[j], 0, 0, 0);
        }
        __syncthreads();
    }
#pragma unroll
    for (int j = 0; j < 12; ++j) {
        int col = (wv * 12 + j) * 16 + fm;
#pragma unroll
        for (int r = 0; r < 4; ++r) {
            int m = m0 + q * 4 + r;
            xz[(size_t)m * 768 + col] = acc2[j][r];
        }
    }
}

// ---------------- conv + silu + x_proj + dt(softplus) (R7) ----------------
__global__ __launch_bounds__(256) void conv_xproj_dt(
    const float* __restrict__ xz, const float* __restrict__ cw,
    const float* __restrict__ cb, const float* __restrict__ xpw,
    const float* __restrict__ dtw, const float* __restrict__ dtb,
    float* __restrict__ u, float* __restrict__ dtg, float* __restrict__ bcg)
{
    __shared__ float su[4][97];
    __shared__ float sx[44];
    int blk = blockIdx.x;
    int b = blk / LSEQ, l = blk % LSEQ;
    int tid = threadIdx.x;
    for (int d = tid; d < DINNER; d += 256) {
        float acc = cb[d];
        float4 w4 = *(const float4*)&cw[d * 4];
        int li = l - 3;
        if (li >= 0)     acc += xz[(size_t)(b * LSEQ + li    ) * 768 + d] * w4.x;
        if (li + 1 >= 0) acc += xz[(size_t)(b * LSEQ + li + 1) * 768 + d] * w4.y;
        if (li + 2 >= 0) acc += xz[(size_t)(b * LSEQ + li + 2) * 768 + d] * w4.z;
        acc += xz[(size_t)(b * LSEQ + l) * 768 + d] * w4.w;
        float sig = 1.f / (1.f + __expf(-acc));
        float val = acc * sig;
        su[d / 96][d % 96] = val;
        u[(size_t)(b * LSEQ + l) * DINNER + d] = val;
    }
    __syncthreads();
    if (tid < 176) {
        int e = tid >> 2, p = tid & 3;
        float acc = 0.f;
        const float* wr = &xpw[e * DINNER + p * 96];
        const float* ur = &su[p][0];
#pragma unroll 8
        for (int j = 0; j < 96; ++j) acc += ur[j] * wr[j];
        acc += __shfl_xor(acc, 1);
        acc += __shfl_xor(acc, 2);
        if (p == 0) sx[e] = acc;
    }
    __syncthreads();
    for (int d = tid; d < DINNER; d += 256) {
        float acc = dtb[d];
#pragma unroll
        for (int r = 0; r < DTRANK; ++r) acc += sx[r] * dtw[d * DTRANK + r];
        float sp = (acc > 20.f) ? acc : log1pf(__expf(acc));
        dtg[(size_t)(b * LSEQ + l) * DINNER + d] = sp;
    }
    if (tid < 32) bcg[(b * LSEQ + l) * 32 + tid] = sx[DTRANK + tid];
}

// ---------------- selective scan + gating (3-phase, R7) ----------------
#define SPAD 272
__global__ __launch_bounds__(256) void scan_kernel(
    const float* __restrict__ u, const float* __restrict__ dtg,
    const float* __restrict__ bc, const float* __restrict__ xz,
    const float* __restrict__ Alog, const float* __restrict__ Dp,
    __hip_bfloat16* __restrict__ y)
{
    __shared__ float sdt[TCH][16];
    __shared__ float su_[TCH][16];
    __shared__ float sz_[TCH][16];
    __shared__ float sB_[TCH][16];
    __shared__ float sC_[TCH][16];
    __shared__ float sprod[TCH][SPAD];

    int b  = blockIdx.x / 24;
    int dg = blockIdx.x % 24;
    int tid = threadIdx.x;
    int s = tid & 15, dl = tid >> 4;
    int d = dg * 16 + dl;
    float Ads = -expf(Alog[d * DSTATE + s]);
    float Dd2 = Dp[dg * 16 + (tid & 15)];
    float h = 0.f;

    for (int c0 = 0; c0 < LSEQ; c0 += TCH) {
        if (tid < TCH * 4) {
            int t = tid >> 2, j4 = (tid & 3) * 4;
            size_t tok = (size_t)(b * LSEQ + c0 + t);
            *(float4*)&sdt[t][j4] = *(const float4*)&dtg[tok * DINNER + dg * 16 + j4];
            *(float4*)&su_[t][j4] = *(const float4*)&u  [tok * DINNER + dg * 16 + j4];
            *(float4*)&sz_[t][j4] = *(const float4*)&xz [tok * 768 + DINNER + dg * 16 + j4];
            *(float4*)&sB_[t][j4] = *(const float4*)&bc [tok * 32 + j4];
            *(float4*)&sC_[t][j4] = *(const float4*)&bc [tok * 32 + 16 + j4];
        }
        __syncthreads();

#pragma unroll 7
        for (int t = 0; t < TCH; ++t) {
            float dtv = sdt[t][dl];
            float uv  = su_[t][dl];
            float Bv  = sB_[t][s];
            float Cv  = sC_[t][s];
            float dA  = __expf(dtv * Ads);
            h = dA * h + (dtv * uv) * Bv;
            sprod[t][dl * 17 + s] = h * Cv;
        }
        __syncthreads();

        for (int i = tid; i < TCH * 16; i += 256) {
            int t = i >> 4, dl2 = i & 15;
            float sum = 0.f;
#pragma unroll
            for (int j = 0; j < 16; ++j) sum += sprod[t][dl2 * 17 + j];
            float uv = su_[t][dl2];
            float zv = sz_[t][dl2];
            float sig = 1.f / (1.f + __expf(-zv));
            y[(size_t)(b * LSEQ + c0 + t) * DINNER + dg * 16 + dl2] =
                __float2bfloat16((sum + uv * Dd2) * (zv * sig));
        }
        __syncthreads();
    }
}

// ---------------------------------------------------------------------------
extern "C" void kernel_launch(void* const* d_in, const int* in_sizes, int n_in,
                              void* d_out, int out_size, void* d_ws, size_t ws_size,
                              hipStream_t stream)
{
    const float* x         = (const float*)d_in[0];
    const float* pe_w      = (const float*)d_in[1];
    const float* pe_b      = (const float*)d_in[2];
    const float* norm_w    = (const float*)d_in[3];
    const float* norm_b    = (const float*)d_in[4];
    const float* in_proj_w = (const float*)d_in[5];
    const float* conv_w    = (const float*)d_in[6];
    const float* conv_b    = (const float*)d_in[7];
    const float* xproj_w   = (const float*)d_in[8];
    const float* dtproj_w  = (const float*)d_in[9];
    const float* dtproj_b  = (const float*)d_in[10];
    const float* A_log     = (const float*)d_in[11];
    const float* D_param   = (const float*)d_in[12];
    const float* outproj_w = (const float*)d_in[13];
    const float* normf_w   = (const float*)d_in[14];
    const float* normf_b   = (const float*)d_in[15];

    float* ws = (float*)d_ws;
    float* residual = ws;                       // 301056 f32
    float* xz       = residual + 301056;        // 1204224 f32
    float* ubuf     = xz + 1204224;             // 602112 f32
    float* dtbuf    = ubuf + 602112;            // 602112 f32
    float* bcbuf    = dtbuf + 602112;           // 50176 f32
    __hip_bfloat16* hn      = (__hip_bfloat16*)(ws + 2759680);  // 301056 bf16
    __hip_bfloat16* ybf     = (__hip_bfloat16*)(ws + 2910208);  // 602112 bf16
    __hip_bfloat16* patches = (__hip_bfloat16*)(ws + 3211264);  // 1204224 bf16
    short* w_in  = (short*)(ws + 3813376);      // 3538944 bf16
    short* w_out = (short*)(ws + 5582848);      // 1769472 bf16
    short* w_pe  = (short*)(ws + 6467584);      // 147456 bf16

    cvt_weights<<<5328, 256, 0, stream>>>(
        in_proj_w, outproj_w, pe_w, w_in, w_out, w_pe);
    im2col<<<4704, 256, 0, stream>>>(x, patches);
    gemm_ln_pe<768><<<98, 256, 0, stream>>>(
        patches, w_pe, pe_b, residual, hn, norm_w, norm_b);
    gemm_in<192><<<dim3(25, 12), 256, 0, stream>>>(hn, w_in, xz, NTOK, 768);

    for (int i = 0; i < DEPTH; ++i) {
        int last = (i == DEPTH - 1);
        conv_xproj_dt<<<NTOK, 256, 0, stream>>>(
            xz, conv_w + (size_t)i * DINNER * 4, conv_b + (size_t)i * DINNER,
            xproj_w + (size_t)i * 44 * DINNER, dtproj_w + (size_t)i * DINNER * DTRANK,
            dtproj_b + (size_t)i * DINNER, ubuf, dtbuf, bcbuf);
        scan_kernel<<<192, 256, 0, stream>>>(
            ubuf, dtbuf, bcbuf, xz, A_log + (size_t)i * DINNER * DSTATE,
            D_param + (size_t)i * DINNER, ybf);
        fused_oln_in<<<98, 256, 0, stream>>>(
            ybf, w_out + (size_t)i * DMODEL * DINNER,
            last ? nullptr : w_in + (size_t)(i + 1) * 768 * DMODEL,
            residual, xz,
            last ? (float*)d_out : nullptr,
            last ? normf_w : norm_w + (i + 1) * DMODEL,
            last ? normf_b : norm_b + (i + 1) * DMODEL);
    }
}

// Round 11
// 1471.143 us; speedup vs baseline: 4.7264x; 1.1296x over previous
//
#include <hip/hip_runtime.h>
#include <hip/hip_bf16.h>

// ---------------------------------------------------------------------------
// VisionMamba, round 10: R7 structure + transposed xproj/dtproj weights.
// B=8, L=196, D_MODEL=192, D_INNER=384, D_STATE=16, DT_RANK=12, DEPTH=24.
//
// R10: R8 (grid.sync ~60us each) and R9 (LN-fused in_proj capped at 98 blocks,
// LDS-staging-bound) both regressed — R7's 4-kernel layout stands. This round
// fixes R7's one quantified defect: conv_xproj_dt read xpw/dtw with one row
// PER LANE (~44-64 cache-line splits per wave-load, ~240us total TA cost).
// cvt_xproj now produces xpwT[k][e] and dtwT[r][d]; the x_proj loop reads
// ~4 lines/iter and dt reads are coalesced. Numerically identical (fp32,
// same accumulation order).
// ---------------------------------------------------------------------------

#define NTOK   1568   // B * L
#define DMODEL 192
#define DINNER 384
#define DSTATE 16
#define DTRANK 12
#define DEPTH  24
#define LSEQ   196
#define TCH    49     // scan time-chunk (196 = 4*49)
#define LDA    40     // LDS row stride in bf16 elements (80B)

typedef __attribute__((ext_vector_type(8))) short short8;
typedef __attribute__((ext_vector_type(4))) short short4v;
typedef __attribute__((ext_vector_type(4))) float floatx4;

__device__ inline short f2bf(float f) {
    __hip_bfloat16 h = __float2bfloat16(f);
    return *reinterpret_cast<short*>(&h);
}

// ---------------- weight fp32 -> bf16 conversion (in/out/pe) ----------------
#define CVT_N1 884736   // in_proj  24*768*192 /4
#define CVT_N2 442368   // out_proj 24*192*384 /4
#define CVT_N3 36864    // pe       192*768    /4
__global__ __launch_bounds__(256) void cvt_weights(
    const float* __restrict__ inw, const float* __restrict__ outw,
    const float* __restrict__ pew,
    short* __restrict__ w_in, short* __restrict__ w_out,
    short* __restrict__ w_pe)
{
    int idx = blockIdx.x * 256 + threadIdx.x;
    float4 v;
    short* dst;
    if (idx < CVT_N1) {
        v = ((const float4*)inw)[idx]; dst = w_in + (size_t)idx * 4;
    } else if (idx < CVT_N1 + CVT_N2) {
        int i = idx - CVT_N1;
        v = ((const float4*)outw)[i]; dst = w_out + (size_t)i * 4;
    } else if (idx < CVT_N1 + CVT_N2 + CVT_N3) {
        int i = idx - CVT_N1 - CVT_N2;
        v = ((const float4*)pew)[i]; dst = w_pe + (size_t)i * 4;
    } else {
        return;
    }
    short4v o;
    o[0] = f2bf(v.x); o[1] = f2bf(v.y); o[2] = f2bf(v.z); o[3] = f2bf(v.w);
    *(short4v*)dst = o;
}

// ---------------- xproj/dtproj transpose (fp32, coalesced-read layouts) ----------------
// xpwT[layer][k=384][e=44] = xpw[layer][e][k];  dtwT[layer][r=12][d=384] = dtw[layer][d][r]
#define XPT_N 405504   // 24*384*44
#define DTT_N 110592   // 24*12*384
__global__ __launch_bounds__(256) void cvt_xproj(
    const float* __restrict__ xpw, const float* __restrict__ dtw,
    float* __restrict__ xpwT, float* __restrict__ dtwT)
{
    int idx = blockIdx.x * 256 + threadIdx.x;
    if (idx < XPT_N) {
        int layer = idx / 16896, rem = idx % 16896;
        int k = rem / 44, e = rem % 44;
        xpwT[idx] = xpw[(size_t)layer * 16896 + e * 384 + k];
    } else if (idx < XPT_N + DTT_N) {
        int i = idx - XPT_N;
        int layer = i / 4608, rem = i % 4608;
        int r = rem / 384, d = rem % 384;
        dtwT[i] = dtw[(size_t)layer * 4608 + d * 12 + r];
    }
}

// ---------------- im2col for patch embed (bf16 out) ----------------
__global__ __launch_bounds__(256) void im2col(
    const float* __restrict__ x, __hip_bfloat16* __restrict__ patches)
{
    int idx = blockIdx.x * 256 + threadIdx.x;
    if (idx >= NTOK * 768) return;
    int tok = idx / 768, e = idx % 768;
    int b = tok / LSEQ, l = tok % LSEQ;
    int py = l / 14, px = l % 14;
    int ic = e >> 8, rem = e & 255, ky = rem >> 4, kx = rem & 15;
    patches[idx] = __float2bfloat16(x[((b * 3 + ic) * 224 + py * 16 + ky) * 224 + px * 16 + kx]);
}

// ---------------- gemm_in: xz[M,768] = hn[M,192] @ W[768,192]^T ----------------
template<int K>
__global__ __launch_bounds__(256) void gemm_in(
    const __hip_bfloat16* __restrict__ A, const short* __restrict__ Wb,
    float* __restrict__ C, int M, int N)
{
    __shared__ short As[64 * LDA];
    __shared__ short Ws[64 * LDA];
    int tid = threadIdx.x;
    int m0 = blockIdx.x * 64, n0 = blockIdx.y * 64;
    int wv = tid >> 6, lane = tid & 63;
    int fm = lane & 15, q = lane >> 4;
    int row = tid >> 2, kc = (tid & 3) * 8;
    const short* Ab = (const short*)A;
    floatx4 acc[4];
#pragma unroll
    for (int nt = 0; nt < 4; ++nt) acc[nt] = (floatx4){0.f, 0.f, 0.f, 0.f};

#pragma unroll
    for (int k0 = 0; k0 < K; k0 += 32) {
        {
            int m = m0 + row;
            short8 v = {0,0,0,0,0,0,0,0};
            if (m < M) v = *(const short8*)&Ab[(size_t)m * K + k0 + kc];
            *(short8*)&As[row * LDA + kc] = v;
        }
        {
            short8 w = *(const short8*)&Wb[(size_t)(n0 + row) * K + k0 + kc];
            *(short8*)&Ws[row * LDA + kc] = w;
        }
        __syncthreads();
        short8 af = *(const short8*)&As[(wv * 16 + fm) * LDA + q * 8];
#pragma unroll
        for (int nt = 0; nt < 4; ++nt) {
            short8 bf = *(const short8*)&Ws[(nt * 16 + fm) * LDA + q * 8];
            acc[nt] = __builtin_amdgcn_mfma_f32_16x16x32_bf16(af, bf, acc[nt], 0, 0, 0);
        }
        __syncthreads();
    }
#pragma unroll
    for (int nt = 0; nt < 4; ++nt) {
        int col = n0 + nt * 16 + fm;
#pragma unroll
        for (int r = 0; r < 4; ++r) {
            int mrow = m0 + wv * 16 + q * 4 + r;
            if (mrow < M) C[(size_t)mrow * N + col] = acc[nt][r];
        }
    }
}

// ---------------- gemm_ln: 16-row tiles, pipelined LDS, fused residual+LN ----------------
template<int K>
__global__ __launch_bounds__(256) void gemm_ln(
    const __hip_bfloat16* __restrict__ A, const short* __restrict__ Wb,
    const float* __restrict__ bias, float* __restrict__ residual,
    __hip_bfloat16* __restrict__ hn, float* __restrict__ outf,
    const float* __restrict__ lnw, const float* __restrict__ lnb,
    int accumulate)
{
    __shared__ short As[16 * LDA];
    __shared__ short Ws[192 * LDA];
    __shared__ float slw[192], slb[192], sbias[192];
    __shared__ float sS1[4][16], sS2[4][16];
    int tid = threadIdx.x;
    int m0 = blockIdx.x * 16;
    int wv = tid >> 6, lane = tid & 63;
    int fm = lane & 15, q = lane >> 4;
    int wrow = tid >> 2, kc = (tid & 3) * 8;
    if (tid < 192) {
        slw[tid] = lnw[tid];
        slb[tid] = lnb[tid];
        sbias[tid] = bias ? bias[tid] : 0.f;
    }
    const short* Ab = (const short*)A;
    floatx4 acc[3];
#pragma unroll
    for (int j = 0; j < 3; ++j) acc[j] = (floatx4){0.f, 0.f, 0.f, 0.f};

    short8 aR = {0,0,0,0,0,0,0,0};
    short8 wR[3];
    if (tid < 64) aR = *(const short8*)&Ab[(size_t)(m0 + (tid >> 2)) * K + kc];
#pragma unroll
    for (int j = 0; j < 3; ++j)
        wR[j] = *(const short8*)&Wb[(size_t)(wrow + 64 * j) * K + kc];

    for (int k0 = 0; k0 < K; k0 += 32) {
        if (tid < 64) *(short8*)&As[(tid >> 2) * LDA + kc] = aR;
#pragma unroll
        for (int j = 0; j < 3; ++j)
            *(short8*)&Ws[(wrow + 64 * j) * LDA + kc] = wR[j];
        __syncthreads();
        int kn = k0 + 32;
        if (kn < K) {
            if (tid < 64) aR = *(const short8*)&Ab[(size_t)(m0 + (tid >> 2)) * K + kn + kc];
#pragma unroll
            for (int j = 0; j < 3; ++j)
                wR[j] = *(const short8*)&Wb[(size_t)(wrow + 64 * j) * K + kn + kc];
        }
        short8 af = *(const short8*)&As[fm * LDA + q * 8];
#pragma unroll
        for (int j = 0; j < 3; ++j) {
            int ct = wv * 3 + j;
            short8 bf = *(const short8*)&Ws[(ct * 16 + fm) * LDA + q * 8];
            acc[j] = __builtin_amdgcn_mfma_f32_16x16x32_bf16(af, bf, acc[j], 0, 0, 0);
        }
        __syncthreads();
    }

    float v[3][4];
#pragma unroll
    for (int r = 0; r < 4; ++r) {
        int m = m0 + q * 4 + r;
#pragma unroll
        for (int j = 0; j < 3; ++j) {
            int col = (wv * 3 + j) * 16 + fm;
            float t = acc[j][r] + sbias[col];
            if (accumulate) t += residual[(size_t)m * DMODEL + col];
            v[j][r] = t;
        }
    }
#pragma unroll
    for (int r = 0; r < 4; ++r) {
        int m = m0 + q * 4 + r;
#pragma unroll
        for (int j = 0; j < 3; ++j)
            residual[(size_t)m * DMODEL + (wv * 3 + j) * 16 + fm] = v[j][r];
    }
#pragma unroll
    for (int r = 0; r < 4; ++r) {
        float s1 = v[0][r] + v[1][r] + v[2][r];
        float s2 = v[0][r]*v[0][r] + v[1][r]*v[1][r] + v[2][r]*v[2][r];
        s1 += __shfl_xor(s1, 1); s2 += __shfl_xor(s2, 1);
        s1 += __shfl_xor(s1, 2); s2 += __shfl_xor(s2, 2);
        s1 += __shfl_xor(s1, 4); s2 += __shfl_xor(s2, 4);
        s1 += __shfl_xor(s1, 8); s2 += __shfl_xor(s2, 8);
        if (fm == 0) { sS1[wv][q * 4 + r] = s1; sS2[wv][q * 4 + r] = s2; }
    }
    __syncthreads();
#pragma unroll
    for (int r = 0; r < 4; ++r) {
        int row = q * 4 + r;
        int m = m0 + row;
        float S1 = sS1[0][row] + sS1[1][row] + sS1[2][row] + sS1[3][row];
        float S2 = sS2[0][row] + sS2[1][row] + sS2[2][row] + sS2[3][row];
        float mean = S1 * (1.f / DMODEL);
        float var  = S2 * (1.f / DMODEL) - mean * mean;
        float rstd = rsqrtf(var + 1e-5f);
#pragma unroll
        for (int j = 0; j < 3; ++j) {
            int col = (wv * 3 + j) * 16 + fm;
            float o = (v[j][r] - mean) * rstd * slw[col] + slb[col];
            if (outf) outf[(size_t)m * DMODEL + col] = o;
            else      hn[(size_t)m * DMODEL + col] = __float2bfloat16(o);
        }
    }
}

// ---------------- conv + silu + x_proj + dt(softplus) ----------------
// R7 structure; x_proj reads transposed xpwT[k][e] (~4 lines/wave-iter vs
// ~44-64 before), dt reads transposed dtwT[r][d] (coalesced).
__global__ __launch_bounds__(256) void conv_xproj_dt(
    const float* __restrict__ xz, const float* __restrict__ cw,
    const float* __restrict__ cb, const float* __restrict__ xpwT,
    const float* __restrict__ dtwT, const float* __restrict__ dtb,
    float* __restrict__ u, float* __restrict__ dtg, float* __restrict__ bcg)
{
    __shared__ float su[4][97];
    __shared__ float sx[44];
    int blk = blockIdx.x;
    int b = blk / LSEQ, l = blk % LSEQ;
    int tid = threadIdx.x;
    for (int d = tid; d < DINNER; d += 256) {
        float acc = cb[d];
        float4 w4 = *(const float4*)&cw[d * 4];
        int li = l - 3;
        if (li >= 0)     acc += xz[(size_t)(b * LSEQ + li    ) * 768 + d] * w4.x;
        if (li + 1 >= 0) acc += xz[(size_t)(b * LSEQ + li + 1) * 768 + d] * w4.y;
        if (li + 2 >= 0) acc += xz[(size_t)(b * LSEQ + li + 2) * 768 + d] * w4.z;
        acc += xz[(size_t)(b * LSEQ + l) * 768 + d] * w4.w;
        float sig = 1.f / (1.f + __expf(-acc));
        float val = acc * sig;
        su[d / 96][d % 96] = val;
        u[(size_t)(b * LSEQ + l) * DINNER + d] = val;
    }
    __syncthreads();
    if (tid < 176) {
        int e = tid >> 2, p = tid & 3;
        float acc = 0.f;
        const float* ur = &su[p][0];
        const float* wt = &xpwT[p * 96 * 44 + e];
#pragma unroll 8
        for (int j = 0; j < 96; ++j) acc += ur[j] * wt[j * 44];
        acc += __shfl_xor(acc, 1);
        acc += __shfl_xor(acc, 2);
        if (p == 0) sx[e] = acc;
    }
    __syncthreads();
    for (int d = tid; d < DINNER; d += 256) {
        float acc = dtb[d];
#pragma unroll
        for (int r = 0; r < DTRANK; ++r) acc += sx[r] * dtwT[r * 384 + d];
        float sp = (acc > 20.f) ? acc : log1pf(__expf(acc));
        dtg[(size_t)(b * LSEQ + l) * DINNER + d] = sp;
    }
    if (tid < 32) bcg[(b * LSEQ + l) * 32 + tid] = sx[DTRANK + tid];
}

// ---------------- selective scan + gating (3-phase, R7) ----------------
#define SPAD 272
__global__ __launch_bounds__(256) void scan_kernel(
    const float* __restrict__ u, const float* __restrict__ dtg,
    const float* __restrict__ bc, const float* __restrict__ xz,
    const float* __restrict__ Alog, const float* __restrict__ Dp,
    __hip_bfloat16* __restrict__ y)
{
    __shared__ float sdt[TCH][16];
    __shared__ float su_[TCH][16];
    __shared__ float sz_[TCH][16];
    __shared__ float sB_[TCH][16];
    __shared__ float sC_[TCH][16];
    __shared__ float sprod[TCH][SPAD];

    int b  = blockIdx.x / 24;
    int dg = blockIdx.x % 24;
    int tid = threadIdx.x;
    int s = tid & 15, dl = tid >> 4;
    int d = dg * 16 + dl;
    float Ads = -expf(Alog[d * DSTATE + s]);
    float Dd2 = Dp[dg * 16 + (tid & 15)];
    float h = 0.f;

    for (int c0 = 0; c0 < LSEQ; c0 += TCH) {
        if (tid < TCH * 4) {
            int t = tid >> 2, j4 = (tid & 3) * 4;
            size_t tok = (size_t)(b * LSEQ + c0 + t);
            *(float4*)&sdt[t][j4] = *(const float4*)&dtg[tok * DINNER + dg * 16 + j4];
            *(float4*)&su_[t][j4] = *(const float4*)&u  [tok * DINNER + dg * 16 + j4];
            *(float4*)&sz_[t][j4] = *(const float4*)&xz [tok * 768 + DINNER + dg * 16 + j4];
            *(float4*)&sB_[t][j4] = *(const float4*)&bc [tok * 32 + j4];
            *(float4*)&sC_[t][j4] = *(const float4*)&bc [tok * 32 + 16 + j4];
        }
        __syncthreads();

#pragma unroll 7
        for (int t = 0; t < TCH; ++t) {
            float dtv = sdt[t][dl];
            float uv  = su_[t][dl];
            float Bv  = sB_[t][s];
            float Cv  = sC_[t][s];
            float dA  = __expf(dtv * Ads);
            h = dA * h + (dtv * uv) * Bv;
            sprod[t][dl * 17 + s] = h * Cv;
        }
        __syncthreads();

        for (int i = tid; i < TCH * 16; i += 256) {
            int t = i >> 4, dl2 = i & 15;
            float sum = 0.f;
#pragma unroll
            for (int j = 0; j < 16; ++j) sum += sprod[t][dl2 * 17 + j];
            float uv = su_[t][dl2];
            float zv = sz_[t][dl2];
            float sig = 1.f / (1.f + __expf(-zv));
            y[(size_t)(b * LSEQ + c0 + t) * DINNER + dg * 16 + dl2] =
                __float2bfloat16((sum + uv * Dd2) * (zv * sig));
        }
        __syncthreads();
    }
}

// ---------------------------------------------------------------------------
extern "C" void kernel_launch(void* const* d_in, const int* in_sizes, int n_in,
                              void* d_out, int out_size, void* d_ws, size_t ws_size,
                              hipStream_t stream)
{
    const float* x         = (const float*)d_in[0];
    const float* pe_w      = (const float*)d_in[1];
    const float* pe_b      = (const float*)d_in[2];
    const float* norm_w    = (const float*)d_in[3];
    const float* norm_b    = (const float*)d_in[4];
    const float* in_proj_w = (const float*)d_in[5];
    const float* conv_w    = (const float*)d_in[6];
    const float* conv_b    = (const float*)d_in[7];
    const float* xproj_w   = (const float*)d_in[8];
    const float* dtproj_w  = (const float*)d_in[9];
    const float* dtproj_b  = (const float*)d_in[10];
    const float* A_log     = (const float*)d_in[11];
    const float* D_param   = (const float*)d_in[12];
    const float* outproj_w = (const float*)d_in[13];
    const float* normf_w   = (const float*)d_in[14];
    const float* normf_b   = (const float*)d_in[15];

    float* ws = (float*)d_ws;
    float* residual = ws;                       // 301056 f32
    float* xz       = residual + 301056;        // 1204224 f32
    float* ubuf     = xz + 1204224;             // 602112 f32
    float* dtbuf    = ubuf + 602112;            // 602112 f32
    float* bcbuf    = dtbuf + 602112;           // 50176 f32
    __hip_bfloat16* hn      = (__hip_bfloat16*)(ws + 2759680);  // 301056 bf16
    __hip_bfloat16* ybf     = (__hip_bfloat16*)(ws + 2910208);  // 602112 bf16
    __hip_bfloat16* patches = (__hip_bfloat16*)(ws + 3211264);  // 1204224 bf16
    short* w_in  = (short*)(ws + 3813376);      // 3538944 bf16
    short* w_out = (short*)(ws + 5582848);      // 1769472 bf16
    short* w_pe  = (short*)(ws + 6467584);      // 147456 bf16
    float* xpwT  = ws + 6541312;                // 405504 f32
    float* dtwT  = xpwT + 405504;               // 110592 f32

    cvt_weights<<<5328, 256, 0, stream>>>(
        in_proj_w, outproj_w, pe_w, w_in, w_out, w_pe);
    cvt_xproj<<<2016, 256, 0, stream>>>(xproj_w, dtproj_w, xpwT, dtwT);
    im2col<<<4704, 256, 0, stream>>>(x, patches);
    gemm_ln<768><<<98, 256, 0, stream>>>(
        patches, w_pe, pe_b, residual, hn, nullptr, norm_w, norm_b, 0);

    for (int i = 0; i < DEPTH; ++i) {
        int last = (i == DEPTH - 1);
        gemm_in<192><<<dim3(25, 12), 256, 0, stream>>>(
            hn, w_in + (size_t)i * 768 * DMODEL, xz, NTOK, 768);
        conv_xproj_dt<<<NTOK, 256, 0, stream>>>(
            xz, conv_w + (size_t)i * DINNER * 4, conv_b + (size_t)i * DINNER,
            xpwT + (size_t)i * 384 * 44, dtwT + (size_t)i * 12 * 384,
            dtproj_b + (size_t)i * DINNER, ubuf, dtbuf, bcbuf);
        scan_kernel<<<192, 256, 0, stream>>>(
            ubuf, dtbuf, bcbuf, xz, A_log + (size_t)i * DINNER * DSTATE,
            D_param + (size_t)i * DINNER, ybf);
        gemm_ln<384><<<98, 256, 0, stream>>>(
            ybf, w_out + (size_t)i * DMODEL * DINNER, nullptr, residual, hn,
            last ? (float*)d_out : nullptr,
            last ? normf_w : norm_w + (i + 1) * DMODEL,
            last ? normf_b : norm_b + (i + 1) * DMODEL,
            1);
    }
}

// Round 12
// 1421.335 us; speedup vs baseline: 4.8920x; 1.0350x over previous
//
#include <hip/hip_runtime.h>
#include <hip/hip_bf16.h>

// ---------------------------------------------------------------------------
// VisionMamba, round 11: R10 + 4-token conv blocks + merged pre-stage.
// B=8, L=196, D_MODEL=192, D_INNER=384, D_STATE=16, DT_RANK=12, DEPTH=24.
//
// R11: R10 was neutral vs R7 (~1470). Remaining gap between bottom-up work
// estimates (~15us/layer) and measured (~40us/layer) points at block
// dispatch/ramp: conv_xproj_dt launched 1568 blocks/layer. Now 392 blocks
// (4 tokens each), xin halo tile staged in LDS (kills 4x tap re-reads),
// x_proj = wave-per-token lane-per-output (su reads broadcast, no shuffles).
// cvt_weights+cvt_xproj+im2col merged into one prep dispatch.
// ---------------------------------------------------------------------------

#define NTOK   1568   // B * L
#define DMODEL 192
#define DINNER 384
#define DSTATE 16
#define DTRANK 12
#define DEPTH  24
#define LSEQ   196
#define TCH    49     // scan time-chunk (196 = 4*49)
#define LDA    40     // LDS row stride in bf16 elements (80B)

typedef __attribute__((ext_vector_type(8))) short short8;
typedef __attribute__((ext_vector_type(4))) short short4v;
typedef __attribute__((ext_vector_type(4))) float floatx4;

__device__ inline short f2bf(float f) {
    __hip_bfloat16 h = __float2bfloat16(f);
    return *reinterpret_cast<short*>(&h);
}

// ---------------- merged pre-stage: weight cvt + transposes + im2col ----------------
// idx ranges: [0,884736) in_proj cvt (float4 units); [.., +442368) out_proj;
// [.., +36864) pe; [.., +405504) xpwT; [.., +110592) dtwT; [.., +1204224) im2col.
#define PR1 884736
#define PR2 1327104   // +442368
#define PR3 1363968   // +36864
#define PR4 1769472   // +405504
#define PR5 1880064   // +110592
#define PR6 3084288   // +1204224
__global__ __launch_bounds__(256) void prep(
    const float* __restrict__ inw, const float* __restrict__ outw,
    const float* __restrict__ pew, const float* __restrict__ xpw,
    const float* __restrict__ dtw, const float* __restrict__ x,
    short* __restrict__ w_in, short* __restrict__ w_out,
    short* __restrict__ w_pe, float* __restrict__ xpwT,
    float* __restrict__ dtwT, __hip_bfloat16* __restrict__ patches)
{
    int idx = blockIdx.x * 256 + threadIdx.x;
    if (idx < PR3) {
        float4 v; short* dst;
        if (idx < PR1)      { v = ((const float4*)inw)[idx];        dst = w_in  + (size_t)idx * 4; }
        else if (idx < PR2) { int i = idx - PR1; v = ((const float4*)outw)[i]; dst = w_out + (size_t)i * 4; }
        else                { int i = idx - PR2; v = ((const float4*)pew)[i];  dst = w_pe  + (size_t)i * 4; }
        short4v o;
        o[0] = f2bf(v.x); o[1] = f2bf(v.y); o[2] = f2bf(v.z); o[3] = f2bf(v.w);
        *(short4v*)dst = o;
    } else if (idx < PR4) {
        int i = idx - PR3;                    // xpwT[layer][k][e] = xpw[layer][e][k]
        int layer = i / 16896, rem = i % 16896;
        int k = rem / 44, e = rem % 44;
        xpwT[i] = xpw[(size_t)layer * 16896 + e * 384 + k];
    } else if (idx < PR5) {
        int i = idx - PR4;                    // dtwT[layer][r][d] = dtw[layer][d][r]
        int layer = i / 4608, rem = i % 4608;
        int r = rem / 384, d = rem % 384;
        dtwT[i] = dtw[(size_t)layer * 4608 + d * 12 + r];
    } else if (idx < PR6) {
        int i = idx - PR5;                    // im2col
        int tok = i / 768, e = i % 768;
        int b = tok / LSEQ, l = tok % LSEQ;
        int py = l / 14, px = l % 14;
        int ic = e >> 8, rem = e & 255, ky = rem >> 4, kx = rem & 15;
        patches[i] = __float2bfloat16(x[((b * 3 + ic) * 224 + py * 16 + ky) * 224 + px * 16 + kx]);
    }
}

// ---------------- gemm_in: xz[M,768] = hn[M,192] @ W[768,192]^T ----------------
template<int K>
__global__ __launch_bounds__(256) void gemm_in(
    const __hip_bfloat16* __restrict__ A, const short* __restrict__ Wb,
    float* __restrict__ C, int M, int N)
{
    __shared__ short As[64 * LDA];
    __shared__ short Ws[64 * LDA];
    int tid = threadIdx.x;
    int m0 = blockIdx.x * 64, n0 = blockIdx.y * 64;
    int wv = tid >> 6, lane = tid & 63;
    int fm = lane & 15, q = lane >> 4;
    int row = tid >> 2, kc = (tid & 3) * 8;
    const short* Ab = (const short*)A;
    floatx4 acc[4];
#pragma unroll
    for (int nt = 0; nt < 4; ++nt) acc[nt] = (floatx4){0.f, 0.f, 0.f, 0.f};

#pragma unroll
    for (int k0 = 0; k0 < K; k0 += 32) {
        {
            int m = m0 + row;
            short8 v = {0,0,0,0,0,0,0,0};
            if (m < M) v = *(const short8*)&Ab[(size_t)m * K + k0 + kc];
            *(short8*)&As[row * LDA + kc] = v;
        }
        {
            short8 w = *(const short8*)&Wb[(size_t)(n0 + row) * K + k0 + kc];
            *(short8*)&Ws[row * LDA + kc] = w;
        }
        __syncthreads();
        short8 af = *(const short8*)&As[(wv * 16 + fm) * LDA + q * 8];
#pragma unroll
        for (int nt = 0; nt < 4; ++nt) {
            short8 bf = *(const short8*)&Ws[(nt * 16 + fm) * LDA + q * 8];
            acc[nt] = __builtin_amdgcn_mfma_f32_16x16x32_bf16(af, bf, acc[nt], 0, 0, 0);
        }
        __syncthreads();
    }
#pragma unroll
    for (int nt = 0; nt < 4; ++nt) {
        int col = n0 + nt * 16 + fm;
#pragma unroll
        for (int r = 0; r < 4; ++r) {
            int mrow = m0 + wv * 16 + q * 4 + r;
            if (mrow < M) C[(size_t)mrow * N + col] = acc[nt][r];
        }
    }
}

// ---------------- gemm_ln: 16-row tiles, pipelined LDS, fused residual+LN ----------------
template<int K>
__global__ __launch_bounds__(256) void gemm_ln(
    const __hip_bfloat16* __restrict__ A, const short* __restrict__ Wb,
    const float* __restrict__ bias, float* __restrict__ residual,
    __hip_bfloat16* __restrict__ hn, float* __restrict__ outf,
    const float* __restrict__ lnw, const float* __restrict__ lnb,
    int accumulate)
{
    __shared__ short As[16 * LDA];
    __shared__ short Ws[192 * LDA];
    __shared__ float slw[192], slb[192], sbias[192];
    __shared__ float sS1[4][16], sS2[4][16];
    int tid = threadIdx.x;
    int m0 = blockIdx.x * 16;
    int wv = tid >> 6, lane = tid & 63;
    int fm = lane & 15, q = lane >> 4;
    int wrow = tid >> 2, kc = (tid & 3) * 8;
    if (tid < 192) {
        slw[tid] = lnw[tid];
        slb[tid] = lnb[tid];
        sbias[tid] = bias ? bias[tid] : 0.f;
    }
    const short* Ab = (const short*)A;
    floatx4 acc[3];
#pragma unroll
    for (int j = 0; j < 3; ++j) acc[j] = (floatx4){0.f, 0.f, 0.f, 0.f};

    short8 aR = {0,0,0,0,0,0,0,0};
    short8 wR[3];
    if (tid < 64) aR = *(const short8*)&Ab[(size_t)(m0 + (tid >> 2)) * K + kc];
#pragma unroll
    for (int j = 0; j < 3; ++j)
        wR[j] = *(const short8*)&Wb[(size_t)(wrow + 64 * j) * K + kc];

    for (int k0 = 0; k0 < K; k0 += 32) {
        if (tid < 64) *(short8*)&As[(tid >> 2) * LDA + kc] = aR;
#pragma unroll
        for (int j = 0; j < 3; ++j)
            *(short8*)&Ws[(wrow + 64 * j) * LDA + kc] = wR[j];
        __syncthreads();
        int kn = k0 + 32;
        if (kn < K) {
            if (tid < 64) aR = *(const short8*)&Ab[(size_t)(m0 + (tid >> 2)) * K + kn + kc];
#pragma unroll
            for (int j = 0; j < 3; ++j)
                wR[j] = *(const short8*)&Wb[(size_t)(wrow + 64 * j) * K + kn + kc];
        }
        short8 af = *(const short8*)&As[fm * LDA + q * 8];
#pragma unroll
        for (int j = 0; j < 3; ++j) {
            int ct = wv * 3 + j;
            short8 bf = *(const short8*)&Ws[(ct * 16 + fm) * LDA + q * 8];
            acc[j] = __builtin_amdgcn_mfma_f32_16x16x32_bf16(af, bf, acc[j], 0, 0, 0);
        }
        __syncthreads();
    }

    float v[3][4];
#pragma unroll
    for (int r = 0; r < 4; ++r) {
        int m = m0 + q * 4 + r;
#pragma unroll
        for (int j = 0; j < 3; ++j) {
            int col = (wv * 3 + j) * 16 + fm;
            float t = acc[j][r] + sbias[col];
            if (accumulate) t += residual[(size_t)m * DMODEL + col];
            v[j][r] = t;
        }
    }
#pragma unroll
    for (int r = 0; r < 4; ++r) {
        int m = m0 + q * 4 + r;
#pragma unroll
        for (int j = 0; j < 3; ++j)
            residual[(size_t)m * DMODEL + (wv * 3 + j) * 16 + fm] = v[j][r];
    }
#pragma unroll
    for (int r = 0; r < 4; ++r) {
        float s1 = v[0][r] + v[1][r] + v[2][r];
        float s2 = v[0][r]*v[0][r] + v[1][r]*v[1][r] + v[2][r]*v[2][r];
        s1 += __shfl_xor(s1, 1); s2 += __shfl_xor(s2, 1);
        s1 += __shfl_xor(s1, 2); s2 += __shfl_xor(s2, 2);
        s1 += __shfl_xor(s1, 4); s2 += __shfl_xor(s2, 4);
        s1 += __shfl_xor(s1, 8); s2 += __shfl_xor(s2, 8);
        if (fm == 0) { sS1[wv][q * 4 + r] = s1; sS2[wv][q * 4 + r] = s2; }
    }
    __syncthreads();
#pragma unroll
    for (int r = 0; r < 4; ++r) {
        int row = q * 4 + r;
        int m = m0 + row;
        float S1 = sS1[0][row] + sS1[1][row] + sS1[2][row] + sS1[3][row];
        float S2 = sS2[0][row] + sS2[1][row] + sS2[2][row] + sS2[3][row];
        float mean = S1 * (1.f / DMODEL);
        float var  = S2 * (1.f / DMODEL) - mean * mean;
        float rstd = rsqrtf(var + 1e-5f);
#pragma unroll
        for (int j = 0; j < 3; ++j) {
            int col = (wv * 3 + j) * 16 + fm;
            float o = (v[j][r] - mean) * rstd * slw[col] + slb[col];
            if (outf) outf[(size_t)m * DMODEL + col] = o;
            else      hn[(size_t)m * DMODEL + col] = __float2bfloat16(o);
        }
    }
}

// ---------------- conv + silu + x_proj + dt : 4 tokens/block (392 blocks) ----------------
// xin halo tile (7 tok x 384) staged in LDS; x_proj = wave w -> token w,
// lane e -> output e (su reads broadcast, weights xpwT[k][e] coalesced).
__global__ __launch_bounds__(256) void conv_xproj_dt(
    const float* __restrict__ xz, const float* __restrict__ cw,
    const float* __restrict__ cb, const float* __restrict__ xpwT,
    const float* __restrict__ dtwT, const float* __restrict__ dtb,
    float* __restrict__ u, float* __restrict__ dtg, float* __restrict__ bcg)
{
    __shared__ float sxz[7 * 384];
    __shared__ float su[4 * 384];
    __shared__ float sx[4 * 48];
    int blk = blockIdx.x;
    int b = blk / 49, c = blk % 49;
    int l0 = c * 4;
    int tid = threadIdx.x;

    // stage xin for tokens l0-3 .. l0+3 (zeros before sequence start)
    for (int idx = tid; idx < 7 * 384; idx += 256) {
        int t = idx / 384, d = idx % 384;
        int l = l0 - 3 + t;
        sxz[idx] = (l >= 0) ? xz[(size_t)(b * LSEQ + l) * 768 + d] : 0.f;
    }
    __syncthreads();

    // conv + SiLU, 4 tokens x 384 channels
    for (int idx = tid; idx < 4 * 384; idx += 256) {
        int t = idx / 384, d = idx % 384;
        float4 w4 = *(const float4*)&cw[d * 4];
        float acc = cb[d]
            + sxz[t * 384 + d]       * w4.x
            + sxz[(t + 1) * 384 + d] * w4.y
            + sxz[(t + 2) * 384 + d] * w4.z
            + sxz[(t + 3) * 384 + d] * w4.w;
        float sig = 1.f / (1.f + __expf(-acc));
        float val = acc * sig;
        su[idx] = val;
        u[(size_t)(b * LSEQ + l0 + t) * 384 + d] = val;
    }
    __syncthreads();

    // x_proj: wave wv handles token wv; lane e<44 computes output e
    {
        int wv = tid >> 6, e = tid & 63;
        if (e < 44) {
            float a0 = 0.f, a1 = 0.f, a2 = 0.f, a3 = 0.f;
            const float* ur = &su[wv * 384];
            for (int j = 0; j < 384; j += 4) {
                a0 += ur[j]     * xpwT[(j    ) * 44 + e];
                a1 += ur[j + 1] * xpwT[(j + 1) * 44 + e];
                a2 += ur[j + 2] * xpwT[(j + 2) * 44 + e];
                a3 += ur[j + 3] * xpwT[(j + 3) * 44 + e];
            }
            sx[wv * 48 + e] = (a0 + a1) + (a2 + a3);
        }
    }
    __syncthreads();

    // dt = softplus(sx[:, :12] @ dtwT + dtb)
    for (int idx = tid; idx < 4 * 384; idx += 256) {
        int t = idx / 384, d = idx % 384;
        float acc = dtb[d];
#pragma unroll
        for (int r = 0; r < DTRANK; ++r) acc += sx[t * 48 + r] * dtwT[r * 384 + d];
        float sp = (acc > 20.f) ? acc : log1pf(__expf(acc));
        dtg[(size_t)(b * LSEQ + l0 + t) * 384 + d] = sp;
    }
    // B/C per token
    if (tid < 128) {
        int t = tid >> 5, j = tid & 31;
        bcg[(size_t)(b * LSEQ + l0 + t) * 32 + j] = sx[t * 48 + 12 + j];
    }
}

// ---------------- selective scan + gating (3-phase, R7) ----------------
#define SPAD 272
__global__ __launch_bounds__(256) void scan_kernel(
    const float* __restrict__ u, const float* __restrict__ dtg,
    const float* __restrict__ bc, const float* __restrict__ xz,
    const float* __restrict__ Alog, const float* __restrict__ Dp,
    __hip_bfloat16* __restrict__ y)
{
    __shared__ float sdt[TCH][16];
    __shared__ float su_[TCH][16];
    __shared__ float sz_[TCH][16];
    __shared__ float sB_[TCH][16];
    __shared__ float sC_[TCH][16];
    __shared__ float sprod[TCH][SPAD];

    int b  = blockIdx.x / 24;
    int dg = blockIdx.x % 24;
    int tid = threadIdx.x;
    int s = tid & 15, dl = tid >> 4;
    int d = dg * 16 + dl;
    float Ads = -expf(Alog[d * DSTATE + s]);
    float Dd2 = Dp[dg * 16 + (tid & 15)];
    float h = 0.f;

    for (int c0 = 0; c0 < LSEQ; c0 += TCH) {
        if (tid < TCH * 4) {
            int t = tid >> 2, j4 = (tid & 3) * 4;
            size_t tok = (size_t)(b * LSEQ + c0 + t);
            *(float4*)&sdt[t][j4] = *(const float4*)&dtg[tok * DINNER + dg * 16 + j4];
            *(float4*)&su_[t][j4] = *(const float4*)&u  [tok * DINNER + dg * 16 + j4];
            *(float4*)&sz_[t][j4] = *(const float4*)&xz [tok * 768 + DINNER + dg * 16 + j4];
            *(float4*)&sB_[t][j4] = *(const float4*)&bc [tok * 32 + j4];
            *(float4*)&sC_[t][j4] = *(const float4*)&bc [tok * 32 + 16 + j4];
        }
        __syncthreads();

#pragma unroll 7
        for (int t = 0; t < TCH; ++t) {
            float dtv = sdt[t][dl];
            float uv  = su_[t][dl];
            float Bv  = sB_[t][s];
            float Cv  = sC_[t][s];
            float dA  = __expf(dtv * Ads);
            h = dA * h + (dtv * uv) * Bv;
            sprod[t][dl * 17 + s] = h * Cv;
        }
        __syncthreads();

        for (int i = tid; i < TCH * 16; i += 256) {
            int t = i >> 4, dl2 = i & 15;
            float sum = 0.f;
#pragma unroll
            for (int j = 0; j < 16; ++j) sum += sprod[t][dl2 * 17 + j];
            float uv = su_[t][dl2];
            float zv = sz_[t][dl2];
            float sig = 1.f / (1.f + __expf(-zv));
            y[(size_t)(b * LSEQ + c0 + t) * DINNER + dg * 16 + dl2] =
                __float2bfloat16((sum + uv * Dd2) * (zv * sig));
        }
        __syncthreads();
    }
}

// ---------------------------------------------------------------------------
extern "C" void kernel_launch(void* const* d_in, const int* in_sizes, int n_in,
                              void* d_out, int out_size, void* d_ws, size_t ws_size,
                              hipStream_t stream)
{
    const float* x         = (const float*)d_in[0];
    const float* pe_w      = (const float*)d_in[1];
    const float* pe_b      = (const float*)d_in[2];
    const float* norm_w    = (const float*)d_in[3];
    const float* norm_b    = (const float*)d_in[4];
    const float* in_proj_w = (const float*)d_in[5];
    const float* conv_w    = (const float*)d_in[6];
    const float* conv_b    = (const float*)d_in[7];
    const float* xproj_w   = (const float*)d_in[8];
    const float* dtproj_w  = (const float*)d_in[9];
    const float* dtproj_b  = (const float*)d_in[10];
    const float* A_log     = (const float*)d_in[11];
    const float* D_param   = (const float*)d_in[12];
    const float* outproj_w = (const float*)d_in[13];
    const float* normf_w   = (const float*)d_in[14];
    const float* normf_b   = (const float*)d_in[15];

    float* ws = (float*)d_ws;
    float* residual = ws;                       // 301056 f32
    float* xz       = residual + 301056;        // 1204224 f32
    float* ubuf     = xz + 1204224;             // 602112 f32
    float* dtbuf    = ubuf + 602112;            // 602112 f32
    float* bcbuf    = dtbuf + 602112;           // 50176 f32
    __hip_bfloat16* hn      = (__hip_bfloat16*)(ws + 2759680);  // 301056 bf16
    __hip_bfloat16* ybf     = (__hip_bfloat16*)(ws + 2910208);  // 602112 bf16
    __hip_bfloat16* patches = (__hip_bfloat16*)(ws + 3211264);  // 1204224 bf16
    short* w_in  = (short*)(ws + 3813376);      // 3538944 bf16
    short* w_out = (short*)(ws + 5582848);      // 1769472 bf16
    short* w_pe  = (short*)(ws + 6467584);      // 147456 bf16
    float* xpwT  = ws + 6541312;                // 405504 f32
    float* dtwT  = xpwT + 405504;               // 110592 f32

    prep<<<12048, 256, 0, stream>>>(
        in_proj_w, outproj_w, pe_w, xproj_w, dtproj_w, x,
        w_in, w_out, w_pe, xpwT, dtwT, patches);
    gemm_ln<768><<<98, 256, 0, stream>>>(
        patches, w_pe, pe_b, residual, hn, nullptr, norm_w, norm_b, 0);

    for (int i = 0; i < DEPTH; ++i) {
        int last = (i == DEPTH - 1);
        gemm_in<192><<<dim3(25, 12), 256, 0, stream>>>(
            hn, w_in + (size_t)i * 768 * DMODEL, xz, NTOK, 768);
        conv_xproj_dt<<<392, 256, 0, stream>>>(
            xz, conv_w + (size_t)i * DINNER * 4, conv_b + (size_t)i * DINNER,
            xpwT + (size_t)i * 384 * 44, dtwT + (size_t)i * 12 * 384,
            dtproj_b + (size_t)i * DINNER, ubuf, dtbuf, bcbuf);
        scan_kernel<<<192, 256, 0, stream>>>(
            ubuf, dtbuf, bcbuf, xz, A_log + (size_t)i * DINNER * DSTATE,
            D_param + (size_t)i * DINNER, ybf);
        gemm_ln<384><<<98, 256, 0, stream>>>(
            ybf, w_out + (size_t)i * DMODEL * DINNER, nullptr, residual, hn,
            last ? (float*)d_out : nullptr,
            last ? normf_w : norm_w + (i + 1) * DMODEL,
            last ? normf_b : norm_b + (i + 1) * DMODEL,
            1);
    }
}